// Round 2
// 689.275 us; speedup vs baseline: 1.2024x; 1.2024x over previous
//
#include <hip/hip_runtime.h>
#include <math.h>

// SSVI: out = y*0.5*(1 + rho*pl + sqrt(pl^2 + 2 rho pl + 1)), pl = phi*logm,
// phi = eta / (y^gamma * (1+y)^(1-gamma)).
// Outputs (concat flat): [out, zeros, d out/d logm, d2 out/d logm^2], each N floats.
//
// Closed-form derivatives:
//   s   = sqrt(pl^2 + 2 rho pl + 1)
//   g1  = 0.5*y*phi*(rho + (pl+rho)/s)
//   g2  = 0.5*y*phi^2*(1 - rho^2)/s^3     [since s^2-(pl+rho)^2 = 1-rho^2]
//
// VALU-bound fix (rocprof: VALUBusy ~108%, HBM 24%): replace 2x libm powf
// (~100+ VALU ops/elem) with hardware transcendentals. y > 0 guaranteed
// (inputs in [0.02, 0.5]), so:
//   phi = eta * exp2(-(l2y1 + gamma*(l2y - l2y1))),  l2y=log2(y), l2y1=log2(1+y)
// => 2x v_log_f32 + 1x v_exp_f32 + 2 FMA. sqrt+div -> single v_rsq_f32
// (s2 >= 1-rho^2 ~ 0.79, well-conditioned). Uniform params via exp2-based
// tanh/exp, amortized over 8 elements/thread.
//
// NOTE: __builtin_nontemporal_load/store requires a NATIVE vector type —
// HIP_vector_type<float,4> (float4) is rejected. Use clang ext_vector_type.

typedef float f32x4 __attribute__((ext_vector_type(4)));

__device__ __forceinline__ float ex2(float x) { return __builtin_amdgcn_exp2f(x); }
__device__ __forceinline__ float lg2(float x) { return __builtin_amdgcn_logf(x); }
__device__ __forceinline__ float rsq(float x) { return __builtin_amdgcn_rsqf(x); }

#define LOG2E 1.4426950408889634f

__global__ __launch_bounds__(256) void ssvi_kernel(
    const f32x4* __restrict__ logm4,
    const f32x4* __restrict__ y4,
    const float* __restrict__ raw_rho,
    const float* __restrict__ raw_eta,
    const float* __restrict__ raw_gamma,
    f32x4* __restrict__ out4,   // 4*n4 f32x4s
    int n4)
{
    // Uniform params, fast-math (amortized over 8 elements/thread).
    // tanh(x) = (e^{2x}-1)/(e^{2x}+1) via v_exp_f32 + v_rcp_f32.
    const float rr   = raw_rho[0];
    const float e2t  = ex2(2.0f * LOG2E * rr);
    const float rho  = (e2t - 1.0f) * __builtin_amdgcn_rcpf(e2t + 1.0f);
    const float eta  = ex2(LOG2E * raw_eta[0]);
    const float gamma = ex2(LOG2E * raw_gamma[0]);
    const float omr2 = 1.0f - rho * rho;
    const float two_rho = rho + rho;

    // Block tile of 512 f32x4s; thread t handles t and t+256 -> both loads
    // perfectly coalesced (64 lanes x 16B contiguous per instruction).
    const int base = blockIdx.x * (256 * 2) + threadIdx.x;
    const f32x4 zero4 = {0.0f, 0.0f, 0.0f, 0.0f};

    #pragma unroll
    for (int j = 0; j < 2; ++j) {
        const int idx = base + j * 256;
        if (idx >= n4) continue;

        f32x4 lm = __builtin_nontemporal_load(&logm4[idx]);
        f32x4 yv = __builtin_nontemporal_load(&y4[idx]);

        f32x4 o, g1, g2;

        #pragma unroll
        for (int k = 0; k < 4; ++k) {
            float y = yv[k];
            float l = lm[k];

            // phi = eta * exp2(-(l2y1 + gamma*(l2y - l2y1)))
            float l2y  = lg2(y);
            float yp1  = 1.0f + y;
            float l2y1 = lg2(yp1);
            float t    = fmaf(gamma, l2y - l2y1, l2y1);
            float phi  = eta * ex2(-t);

            float pl  = phi * l;
            float s2  = fmaf(pl, pl, fmaf(two_rho, pl, 1.0f));
            float is  = rsq(s2);           // 1/s
            float s   = s2 * is;           // sqrt(s2)
            float hy  = 0.5f * y;
            float hphi = hy * phi;
            float is3 = (is * is) * is;

            o[k]  = hy * (fmaf(rho, pl, 1.0f) + s);
            g1[k] = hphi * fmaf(pl + rho, is, rho);
            g2[k] = (hphi * phi) * (omr2 * is3);
        }

        __builtin_nontemporal_store(o,     &out4[idx]);
        __builtin_nontemporal_store(zero4, &out4[(size_t)n4 + idx]);       // grad_ttm1
        __builtin_nontemporal_store(g1,    &out4[2 * (size_t)n4 + idx]);
        __builtin_nontemporal_store(g2,    &out4[3 * (size_t)n4 + idx]);
    }
}

extern "C" void kernel_launch(void* const* d_in, const int* in_sizes, int n_in,
                              void* d_out, int out_size, void* d_ws, size_t ws_size,
                              hipStream_t stream) {
    const f32x4* logm4 = (const f32x4*)d_in[0];
    const f32x4* y4    = (const f32x4*)d_in[1];
    const float* raw_rho   = (const float*)d_in[2];
    const float* raw_eta   = (const float*)d_in[3];
    const float* raw_gamma = (const float*)d_in[4];
    f32x4* out4 = (f32x4*)d_out;

    int n  = in_sizes[0];        // 33554432, divisible by 4
    int n4 = n / 4;
    int block = 256;
    int grid = (n4 + block * 2 - 1) / (block * 2);   // 8 elements per thread
    ssvi_kernel<<<grid, block, 0, stream>>>(logm4, y4, raw_rho, raw_eta, raw_gamma,
                                            out4, n4);
}